// Round 1
// baseline (874.274 us; speedup 1.0000x reference)
//
#include <hip/hip_runtime.h>
#include <hip/hip_bf16.h>
#include <hip/hip_cooperative_groups.h>

namespace cg = cooperative_groups;

// EGNN encoder, N=50000, E=250000, D=128, L=4. bf16 inputs/output (verified R2).
// R3: CSR-by-tgt aggregation (no atomics), EW2@NW1b folding.
// R4: 3-stage parallel CSR scan.  R5: agg chunked x4 + fast rcp (VGPR 32 — occupancy
//     is the latency-hider; R8/R9 both regressed by killing it).
// R7: weight-stationary streaming matmuls.  R10: bf16-only residual stream.
// R11: 8 setup kernels merged into one phase-partitioned kernel.
// R12 (this round): entire front-end (detect+memset+hist+bsum+bscan+csr+scatter+setup)
//     merged into ONE cooperative kernel; setup work co-scheduled inside CSR-chain
//     phases so it hides under hist/scan/scatter. Dispatches 24 -> 17.

#define NNODES 50000
#define NEDGES 250000
#define NTILES 3125   // 50000/16 exactly, no tail
#define MMGRID 512
#define RGRID  1024
#define COOPGRID 512  // 2x co-residency margin at <=128 VGPR (launch_bounds 256,4)

typedef unsigned short u16;
typedef __attribute__((ext_vector_type(8))) short bf16x8;
typedef __attribute__((ext_vector_type(4))) float floatx4;

__device__ __forceinline__ float b2f(u16 h){ unsigned u=((unsigned)h)<<16; float f; __builtin_memcpy(&f,&u,4); return f; }
__device__ __forceinline__ u16 f2b(float f){ unsigned u; __builtin_memcpy(&u,&f,4); u = u + 0x7FFFu + ((u>>16)&1u); return (u16)(u>>16); }
__device__ __forceinline__ float siluf(float x){ return x*__builtin_amdgcn_rcpf(1.f+__expf(-x)); }
__device__ __forceinline__ float ldf(const void* p, long i, int isbf){
  return isbf ? b2f(((const u16*)p)[i]) : ((const float*)p)[i];
}

// ---------------- cooperative front-end ----------------
// P0: memset cnt | cvtp | pparm | w2p/c2p | ebW          (596 vblocks)
// P1: hist | pack 24 weight matrices                      (1169 vblocks)
// P2: bsum | W12 = EW2@NW1b -> packed chunks 24..27       (708 vblocks)
// P3: bscan | proj x = nf@npw + npb                       (25001 vblocks)
// P4: csr (rowptr/cursor/degf)                            (196 vblocks)
// P5: scatter (permsrc)                                   (977 vblocks)
#define P0_MEMSET 196
#define P0_CVTP   587
#define P0_END    596
#define P1_HIST   977
#define P1_END    1169
#define P2_BSUM   196
#define P2_END    708
#define P3_END    25001
#define P4_END    196
#define P5_END    977

__global__ __launch_bounds__(256, 4) void coop_setup_kernel(
    const void* __restrict__ lng, int* __restrict__ flag,
    const int* __restrict__ src, const int* __restrict__ tgt,
    int* __restrict__ cnt, int* __restrict__ bsum, int* __restrict__ rowptr,
    int* __restrict__ cursor, float* __restrict__ degf, int* __restrict__ permsrc,
    const void* __restrict__ ew1, const void* __restrict__ ew2,
    const void* __restrict__ nw1, const void* __restrict__ nw2,
    u16* __restrict__ packed,
    const void* __restrict__ eb2, const void* __restrict__ pw1,
    const void* __restrict__ pb1, const void* __restrict__ pw2v, const void* __restrict__ pb2,
    float* __restrict__ w2p, float* __restrict__ c2p, float* __restrict__ pparm,
    float* __restrict__ ebW,
    const void* __restrict__ nf, const void* __restrict__ npw, const void* __restrict__ npb,
    u16* __restrict__ xb,
    const void* __restrict__ pos, float* __restrict__ pf)
{
  cg::grid_group grid = cg::this_grid();
  const int tid = threadIdx.x;
  const int isbf = (((const u16*)lng)[0] != 0) ? 1 : 0;
  __shared__ int slds[256];
  __shared__ float red[128];
  __shared__ int ws4[4];
  if (blockIdx.x == 0 && tid == 0) *flag = isbf;

  // ---- P0: memset cnt | cvtp | pparm | w2p | ebW ----
  for (int vb = blockIdx.x; vb < P0_END; vb += gridDim.x){
    if (vb < P0_MEMSET){
      int i = vb*256 + tid;
      if (i < NNODES) cnt[i] = 0;
    } else if (vb < P0_CVTP){
      int i = (vb - P0_MEMSET)*256 + tid;
      if (i < 2*NNODES) pf[i] = ldf(pos, i, isbf);
    } else if (vb == P0_CVTP){
      if (tid < 4){
        int l = tid;
        pparm[l*4+0] = ldf(pw1, (long)l*129 + 128, isbf);
        pparm[l*4+1] = ldf(pb1, l, isbf);
        pparm[l*4+2] = ldf(pw2v, l, isbf);
        pparm[l*4+3] = ldf(pb2, l, isbf);
      }
    } else if (vb < P0_CVTP + 5){
      int l = vb - (P0_CVTP + 1);
      int i = tid;
      long Woff = (long)l*128*128, poff = (long)l*129;
      if (i < 128){
        float acc = 0.f;
        for (int j=0;j<128;j++) acc += ldf(ew2, Woff + (long)i*128 + j, isbf) * ldf(pw1, poff + j, isbf);
        w2p[l*128+i] = acc;
        red[i] = ldf(eb2, (long)l*128 + i, isbf) * ldf(pw1, poff + i, isbf);
      }
      __syncthreads();
      for (int st=64; st>0; st>>=1){ if (i<st) red[i]+=red[i+st]; __syncthreads(); }
      if (i==0) c2p[l] = red[0];
      __syncthreads();
    } else {
      int l = vb - (P0_CVTP + 5);
      if (tid < 128){
        int j = tid;
        long nb = (long)l*256*128 + 128*128;
        float acc = 0.f;
        for (int d=0; d<128; d++)
          acc += ldf(eb2, (long)l*128 + d, isbf) * ldf(nw1, nb + (long)d*128 + j, isbf);
        ebW[l*128+j] = acc;
      }
    }
  }
  grid.sync();

  // ---- P1: hist | pack ----
  for (int vb = blockIdx.x; vb < P1_END; vb += gridDim.x){
    if (vb < P1_HIST){
      int i = vb*256 + tid;
      if (i < NEDGES) atomicAdd(&cnt[tgt[i]], 1);
    } else {
      int t = (vb - P1_HIST)*256 + tid;
      int m = t >> 11; int r = t & 2047;
      int lane = r & 63; int ntk = r >> 6;
      int kk = ntk >> 3, nt = ntk & 7;
      int l = m/6, w = m%6;
      const void* sp; long off;
      switch(w){
        case 0: sp=ew1; off=(long)l*257*128;            break; // W1a
        case 1: sp=ew1; off=(long)l*257*128 + 128*128;  break; // W1b
        case 2: sp=ew2; off=(long)l*128*128;            break; // EW2 (layout slot)
        case 3: sp=nw1; off=(long)l*256*128;            break; // NW1a
        case 4: sp=nw1; off=(long)l*256*128 + 128*128;  break; // NW1b (unused)
        default:sp=nw2; off=(long)l*128*128;            break; // NW2
      }
      int c  = nt*16 + (lane & 15);
      int k0 = kk*32 + (lane >> 4)*8;
      u16 vals[8];
#pragma unroll
      for (int j=0;j<8;j++){
        long idx = off + (long)(k0+j)*128 + c;
        vals[j] = isbf ? ((const u16*)sp)[idx] : f2b(((const float*)sp)[idx]);
      }
      bf16x8 v; __builtin_memcpy(&v, vals, 16);
      *(bf16x8*)(packed + (long)t*8) = v;
    }
  }
  grid.sync();

  // ---- P2: bsum | W12 ----
  for (int vb = blockIdx.x; vb < P2_END; vb += gridDim.x){
    if (vb < P2_BSUM){
      int i = vb*256 + tid;
      int v = (i < NNODES) ? cnt[i] : 0;
#pragma unroll
      for (int off=32; off; off>>=1) v += __shfl_down(v, off);
      if ((tid & 63) == 0) ws4[tid>>6] = v;
      __syncthreads();
      if (tid == 0) bsum[vb] = ws4[0]+ws4[1]+ws4[2]+ws4[3];
      __syncthreads();
    } else {
      int bb = vb - P2_BSUM;
      int l = bb >> 7, k = bb & 127;
      if (tid < 128){
        int j = tid;
        long e2 = (long)l*16384 + (long)k*128;
        long nb = (long)l*256*128 + 128*128;
        float acc = 0.f;
        for (int d=0; d<128; d++)
          acc += ldf(ew2, e2 + d, isbf) * ldf(nw1, nb + (long)d*128 + j, isbf);
        int kk = k>>5, lane = ((k>>3)&3)*16 + (j&15), nt = j>>4, jj = k&7;
        packed[(long)(24+l)*16384 + (long)((kk*8+nt)*64 + lane)*8 + jj] = f2b(acc);
      }
    }
  }
  grid.sync();

  // ---- P3: bscan | proj ----
  for (int vb = blockIdx.x; vb < P3_END; vb += gridDim.x){
    if (vb == 0){
      int i = tid;
      int v = (i < 196) ? bsum[i] : 0;
      slds[i] = v; __syncthreads();
#pragma unroll
      for (int off=1; off<256; off<<=1){
        int t2 = (i>=off)? slds[i-off] : 0; __syncthreads();
        slds[i] += t2; __syncthreads();
      }
      if (i < 196) bsum[i] = slds[i] - v;  // exclusive prefix
    } else {
      int nblk = vb - 1;
      int n = nblk*2 + (tid>>7), d = tid & 127;
      if (n < NNODES){
        float acc = ldf(npb, d, isbf);
#pragma unroll
        for (int f=0; f<12; f++) acc += ldf(nf, (long)n*12+f, isbf) * ldf(npw, f*128+d, isbf);
        xb[(long)n*128+d] = f2b(acc);
      }
    }
  }
  grid.sync();

  // ---- P4: csr ----
  for (int vb = blockIdx.x; vb < P4_END; vb += gridDim.x){
    int i = vb*256 + tid;
    int c = (i < NNODES) ? cnt[i] : 0;
    slds[tid] = c; __syncthreads();
#pragma unroll
    for (int off=1; off<256; off<<=1){
      int t2 = (tid>=off)? slds[tid-off] : 0; __syncthreads();
      slds[tid] += t2; __syncthreads();
    }
    int run = bsum[vb] + slds[tid] - c;  // exclusive
    if (i < NNODES){
      rowptr[i] = run; cursor[i] = run; degf[i] = (float)c;
      if (i == NNODES-1) rowptr[NNODES] = run + c;
    }
    __syncthreads();
  }
  grid.sync();

  // ---- P5: scatter ----
  for (int vb = blockIdx.x; vb < P5_END; vb += gridDim.x){
    int e = vb*256 + tid;
    if (e < NEDGES){
      int t2 = tgt[e];
      int p = atomicAdd(&cursor[t2], 1);
      permsrc[p] = src[e];
    }
  }
}

// ---------- streaming A/B matmul: Ab = bf16(x@Wa+eb1), Bb = bf16(x@Wb) ----------
__global__ __launch_bounds__(256) void mm_ab_kernel(
    const u16* __restrict__ X, const u16* __restrict__ Wa, const u16* __restrict__ Wb,
    const void* __restrict__ bias, long bias_off,
    u16* __restrict__ Ab, u16* __restrict__ Bb, const int* __restrict__ flagp)
{
  extern __shared__ u16 wlds[];
  const int tid = threadIdx.x, wave = tid>>6, lane = tid&63;
  const int isbf = *flagp;
  const int lr = lane&15, lg = lane>>4;
  for (int i=tid; i<2048; i+=256){
    *(bf16x8*)(wlds + (long)i*8)          = *(const bf16x8*)(Wa + (long)i*8);
    *(bf16x8*)(wlds + 16384 + (long)i*8)  = *(const bf16x8*)(Wb + (long)i*8);
  }
  float biasv[8];
#pragma unroll
  for (int nt=0;nt<8;nt++) biasv[nt] = ldf(bias, bias_off + nt*16 + lr, isbf);
  __syncthreads();
  for (int tile = blockIdx.x*4 + wave; tile < NTILES; tile += MMGRID*4){
    const u16* xr = X + ((long)tile*16 + lr)*128;
    bf16x8 a[4];
#pragma unroll
    for (int kk=0;kk<4;kk++) a[kk] = *(const bf16x8*)(xr + kk*32 + lg*8);
    floatx4 accA[8], accB[8];
#pragma unroll
    for (int i=0;i<8;i++){ accA[i]=(floatx4){0,0,0,0}; accB[i]=(floatx4){0,0,0,0}; }
#pragma unroll
    for (int kk=0;kk<4;kk++){
#pragma unroll
      for (int nt=0;nt<8;nt++){
        bf16x8 ba = *(const bf16x8*)(wlds + ((kk*8+nt)*64 + lane)*8);
        accA[nt] = __builtin_amdgcn_mfma_f32_16x16x32_bf16(a[kk], ba, accA[nt], 0, 0, 0);
        bf16x8 bb = *(const bf16x8*)(wlds + 16384 + ((kk*8+nt)*64 + lane)*8);
        accB[nt] = __builtin_amdgcn_mfma_f32_16x16x32_bf16(a[kk], bb, accB[nt], 0, 0, 0);
      }
    }
#pragma unroll
    for (int r=0;r<4;r++){
      long row = (long)tile*16 + lg*4 + r;
#pragma unroll
      for (int nt=0;nt<8;nt++){
        int col = nt*16 + lr;
        Ab[row*128+col] = f2b(accA[nt][r] + biasv[nt]);
        Bb[row*128+col] = f2b(accB[nt][r]);
      }
    }
  }
}

// ---------- streaming hidden matmul: hb = bf16(silu(xb@NW1a + Hb@W12 + deg*ebW + nb1)) ----------
__global__ __launch_bounds__(256) void mm_hidden_kernel(
    const u16* __restrict__ X, const u16* __restrict__ H,
    const u16* __restrict__ W1, const u16* __restrict__ W2,
    const void* __restrict__ nb1, long nb1_off,
    const float* __restrict__ degf, const float* __restrict__ ebW,
    u16* __restrict__ hb, const int* __restrict__ flagp)
{
  extern __shared__ u16 wlds[];
  const int tid = threadIdx.x, wave = tid>>6, lane = tid&63;
  const int isbf = *flagp;
  const int lr = lane&15, lg = lane>>4;
  for (int i=tid; i<2048; i+=256){
    *(bf16x8*)(wlds + (long)i*8)          = *(const bf16x8*)(W1 + (long)i*8);
    *(bf16x8*)(wlds + 16384 + (long)i*8)  = *(const bf16x8*)(W2 + (long)i*8);
  }
  float nb1v[8], ebv[8];
#pragma unroll
  for (int nt=0;nt<8;nt++){ int col=nt*16+lr; nb1v[nt]=ldf(nb1, nb1_off+col, isbf); ebv[nt]=ebW[col]; }
  __syncthreads();
  for (int tile = blockIdx.x*4 + wave; tile < NTILES; tile += MMGRID*4){
    const u16* xr = X + ((long)tile*16 + lr)*128;
    const u16* hr = H + ((long)tile*16 + lr)*128;
    bf16x8 ax[4], ah[4];
#pragma unroll
    for (int kk=0;kk<4;kk++){
      ax[kk] = *(const bf16x8*)(xr + kk*32 + lg*8);
      ah[kk] = *(const bf16x8*)(hr + kk*32 + lg*8);
    }
    floatx4 acc[8];
#pragma unroll
    for (int i=0;i<8;i++) acc[i]=(floatx4){0,0,0,0};
#pragma unroll
    for (int kk=0;kk<4;kk++){
#pragma unroll
      for (int nt=0;nt<8;nt++){
        bf16x8 b1 = *(const bf16x8*)(wlds + ((kk*8+nt)*64 + lane)*8);
        acc[nt] = __builtin_amdgcn_mfma_f32_16x16x32_bf16(ax[kk], b1, acc[nt], 0, 0, 0);
        bf16x8 b2 = *(const bf16x8*)(wlds + 16384 + ((kk*8+nt)*64 + lane)*8);
        acc[nt] = __builtin_amdgcn_mfma_f32_16x16x32_bf16(ah[kk], b2, acc[nt], 0, 0, 0);
      }
    }
    float dv[4];
#pragma unroll
    for (int r=0;r<4;r++) dv[r] = degf[(long)tile*16 + lg*4 + r];
#pragma unroll
    for (int r=0;r<4;r++){
      long row = (long)tile*16 + lg*4 + r;
#pragma unroll
      for (int nt=0;nt<8;nt++){
        int col = nt*16 + lr;
        hb[row*128+col] = f2b(siluf(acc[nt][r] + nb1v[nt] + dv[r]*ebv[nt]));
      }
    }
  }
}

// ---------- streaming residual matmul (bf16 residual stream), grid RGRID ----------
// LN=0: xb = bf16(b2f(xb) + hb@NW2 + nb2).  LN=1: layernorm -> d_out.
template<int LN>
__global__ __launch_bounds__(256) void mm_res_kernel(
    const u16* __restrict__ H, const u16* __restrict__ W,
    const void* __restrict__ nb2, long nb2_off,
    u16* __restrict__ xb,
    const void* __restrict__ lng, const void* __restrict__ lnb, void* __restrict__ outp,
    const int* __restrict__ flagp)
{
  extern __shared__ u16 wlds[];
  const int tid = threadIdx.x, wave = tid>>6, lane = tid&63;
  const int isbf = *flagp;
  const int lr = lane&15, lg = lane>>4;
  for (int i=tid; i<2048; i+=256)
    *(bf16x8*)(wlds + (long)i*8) = *(const bf16x8*)(W + (long)i*8);
  float nb2v[8];
#pragma unroll
  for (int nt=0;nt<8;nt++) nb2v[nt] = ldf(nb2, nb2_off + nt*16 + lr, isbf);
  float gv[8], bvv[8];
  if (LN){
#pragma unroll
    for (int nt=0;nt<8;nt++){ int col=nt*16+lr; gv[nt]=ldf(lng,col,isbf); bvv[nt]=ldf(lnb,col,isbf); }
  }
  __syncthreads();
  for (int tile = blockIdx.x*4 + wave; tile < NTILES; tile += RGRID*4){
    const u16* hr = H + ((long)tile*16 + lr)*128;
    bf16x8 a[4];
#pragma unroll
    for (int kk=0;kk<4;kk++) a[kk] = *(const bf16x8*)(hr + kk*32 + lg*8);
    floatx4 acc[8];
#pragma unroll
    for (int i=0;i<8;i++) acc[i]=(floatx4){0,0,0,0};
#pragma unroll
    for (int kk=0;kk<4;kk++){
#pragma unroll
      for (int nt=0;nt<8;nt++){
        bf16x8 b = *(const bf16x8*)(wlds + ((kk*8+nt)*64 + lane)*8);
        acc[nt] = __builtin_amdgcn_mfma_f32_16x16x32_bf16(a[kk], b, acc[nt], 0, 0, 0);
      }
    }
#pragma unroll
    for (int r=0;r<4;r++){
      long row = (long)tile*16 + lg*4 + r;
#pragma unroll
      for (int nt=0;nt<8;nt++){
        int col = nt*16 + lr;
        float v = acc[nt][r] + nb2v[nt] + b2f(xb[row*128+col]);
        acc[nt][r] = v;
        if (!LN) xb[row*128+col] = f2b(v);
      }
    }
    if (LN){
      float s[4] = {0,0,0,0}, q[4] = {0,0,0,0};
#pragma unroll
      for (int r=0;r<4;r++){
#pragma unroll
        for (int nt=0;nt<8;nt++){ float v = acc[nt][r]; s[r] += v; q[r] += v*v; }
      }
#pragma unroll
      for (int mask=1; mask<16; mask<<=1){
#pragma unroll
        for (int r=0;r<4;r++){ s[r] += __shfl_xor(s[r], mask); q[r] += __shfl_xor(q[r], mask); }
      }
#pragma unroll
      for (int r=0;r<4;r++){
        long row = (long)tile*16 + lg*4 + r;
        float mu = s[r]*(1.f/128.f);
        float var = q[r]*(1.f/128.f) - mu*mu;
        float inv = rsqrtf(var + 1e-5f);
#pragma unroll
        for (int nt=0;nt<8;nt++){
          int col = nt*16 + lr;
          float y = (acc[nt][r]-mu)*inv*gv[nt] + bvv[nt];
          if (isbf) ((u16*)outp)[row*128+col] = f2b(y);
          else      ((float*)outp)[row*128+col] = y;
        }
      }
    }
  }
}

// ---------- CSR aggregation: one wave per target node, chunked x4 (R5-proven) ----------
__global__ __launch_bounds__(256) void agg_kernel(
    const int* __restrict__ rowptr, const int* __restrict__ permsrc,
    const float* __restrict__ pf_in,
    const u16* __restrict__ A, const u16* __restrict__ B,
    const void* __restrict__ ew1, long w1c_off,
    const float* __restrict__ w2p, const float* __restrict__ c2pl,
    const float* __restrict__ pp,
    u16* __restrict__ Hb, float* __restrict__ pf_out, int N,
    const int* __restrict__ flagp)
{
  const int isbf = *flagp;
  int tid = threadIdx.x, lane = tid & 63;
  int t = blockIdx.x*4 + (tid>>6);
  if (t >= N) return;
  int tu = __builtin_amdgcn_readfirstlane(t);   // wave-uniform -> scalar loads
  float c0 = ldf(ew1, w1c_off + 2*lane,     isbf);
  float c1 = ldf(ew1, w1c_off + 2*lane + 1, isbf);
  float2 wp = *(const float2*)(w2p + 2*lane);
  float c2 = c2pl[0];
  float p0 = pp[0], p1 = pp[1], p2 = pp[2], p3 = pp[3];
  int jb = rowptr[tu], je = rowptr[tu+1];
  float2 pt = *(const float2*)(pf_in + 2*(long)tu);
  unsigned bv = *(const unsigned*)(B + (long)tu*128 + 2*lane);
  float b0 = b2f((u16)bv), b1 = b2f((u16)(bv>>16));
  float h0a = 0.f, h1a = 0.f, dpx = 0.f, dpy = 0.f;
  for (int j0 = jb; j0 < je; j0 += 4){
    int m = je - j0; if (m > 4) m = 4;
    int s[4]; float2 ps[4]; unsigned av[4];
    float part[4], dist[4], dxv[4], dyv[4];
#pragma unroll
    for (int c=0;c<4;c++) if (c<m) s[c] = permsrc[j0+c];
#pragma unroll
    for (int c=0;c<4;c++) if (c<m){
      ps[c] = *(const float2*)(pf_in + 2*(long)s[c]);
      av[c] = *(const unsigned*)(A + (long)s[c]*128 + 2*lane);
    }
#pragma unroll
    for (int c=0;c<4;c++){
      if (c<m){
        float dx = pt.x - ps[c].x, dy = pt.y - ps[c].y;
        float d2 = dx*dx + dy*dy;
        float dd = __builtin_amdgcn_sqrtf(d2);
        float h0 = siluf(b2f((u16)av[c])       + b0 + dd*c0);
        float h1 = siluf(b2f((u16)(av[c]>>16)) + b1 + dd*c1);
        h0a += h0; h1a += h1;
        part[c] = h0*wp.x + h1*wp.y;
        dist[c] = dd; dxv[c] = dx; dyv[c] = dy;
      } else part[c] = 0.f;
    }
#pragma unroll
    for (int off=32; off; off>>=1){
#pragma unroll
      for (int c=0;c<4;c++) part[c] += __shfl_xor(part[c], off);
    }
#pragma unroll
    for (int c=0;c<4;c++){
      if (c<m){
        float spre = part[c] + c2 + dist[c]*p0 + p1;
        float pwv  = siluf(spre)*p2 + p3;
        float inv  = __builtin_amdgcn_rcpf(dist[c] + 1e-6f);
        dpx += dxv[c]*inv*pwv; dpy += dyv[c]*inv*pwv;
      }
    }
  }
  *(unsigned*)(Hb + (long)tu*128 + 2*lane) = (unsigned)f2b(h0a) | ((unsigned)f2b(h1a)<<16);
  if (lane == 0){
    float2 o; o.x = pt.x + dpx; o.y = pt.y + dpy;
    *(float2*)(pf_out + 2*(long)tu) = o;
  }
}

extern "C" void kernel_launch(void* const* d_in, const int* in_sizes, int n_in,
                              void* d_out, int out_size, void* d_ws, size_t ws_size,
                              hipStream_t stream)
{
  const void* nf  = d_in[0];
  const void* pos = d_in[1];
  const void* npw = d_in[3];
  const void* npb = d_in[4];
  const void* ew1 = d_in[7];
  const void* eb1 = d_in[8];
  const void* ew2 = d_in[9];
  const void* eb2 = d_in[10];
  const void* nw1 = d_in[11];
  const void* nb1 = d_in[12];
  const void* nw2 = d_in[13];
  const void* nb2 = d_in[14];
  const void* pw1 = d_in[15];
  const void* pb1 = d_in[16];
  const void* pw2 = d_in[17];
  const void* pb2 = d_in[18];
  const void* lng = d_in[19];
  const void* lnb = d_in[20];
  const int* eidx = (const int*)d_in[21];
  const int N = NNODES, E = NEDGES;
  const int* srcp = eidx;
  const int* tgtp = eidx + E;

  char* w = (char*)d_ws;
  size_t off = 0;
  auto alloc = [&](size_t bytes)->char* { char* p = w + off; off += (bytes + 255)/256*256; return p; };
  u16*   xb    = (u16*)  alloc((size_t)N*128*2);
  u16*   Ab    = (u16*)  alloc((size_t)N*128*2);
  u16*   Bb    = (u16*)  alloc((size_t)N*128*2);
  u16*   Hb    = (u16*)  alloc((size_t)N*128*2);
  float* pf0   = (float*)alloc((size_t)N*2*4);
  float* pf1   = (float*)alloc((size_t)N*2*4);
  int*   cnt   = (int*)  alloc((size_t)N*4);
  int*   rowptr= (int*)  alloc((size_t)(N+1)*4);
  int*   cursor= (int*)  alloc((size_t)N*4);
  float* degf  = (float*)alloc((size_t)N*4);
  int*   perm  = (int*)  alloc((size_t)E*4);
  int*   bsum  = (int*)  alloc(256*4);
  u16*   pk    = (u16*)  alloc((size_t)28*16384*2);
  float* ebW   = (float*)alloc(4*128*4);
  float* w2p   = (float*)alloc(4*128*4);
  float* c2p   = (float*)alloc(4*4);
  float* pparm = (float*)alloc(16*4);
  int*   flag  = (int*)  alloc(4);
  u16* hb = Ab;   // Ab dead after agg_kernel; rewritten by next mm_ab

  // ---- one cooperative front-end kernel replaces 8 dispatches ----
  void* kargs[] = {
    (void*)&lng, (void*)&flag, (void*)&srcp, (void*)&tgtp,
    (void*)&cnt, (void*)&bsum, (void*)&rowptr, (void*)&cursor, (void*)&degf, (void*)&perm,
    (void*)&ew1, (void*)&ew2, (void*)&nw1, (void*)&nw2, (void*)&pk,
    (void*)&eb2, (void*)&pw1, (void*)&pb1, (void*)&pw2, (void*)&pb2,
    (void*)&w2p, (void*)&c2p, (void*)&pparm, (void*)&ebW,
    (void*)&nf, (void*)&npw, (void*)&npb, (void*)&xb,
    (void*)&pos, (void*)&pf0
  };
  hipLaunchCooperativeKernel(coop_setup_kernel, dim3(COOPGRID), dim3(256), kargs, 0, stream);

  // layer 0 A/B from projected x
  mm_ab_kernel<<<MMGRID, 256, 65536, stream>>>(xb, pk + 0*16384, pk + 1*16384,
                                               eb1, 0, Ab, Bb, flag);
  for (int l = 0; l < 4; l++){
    const u16* NW1a = pk + (l*6+3)*16384;
    const u16* NW2p = pk + (l*6+5)*16384;
    const u16* W12p = pk + (24+l)*16384;
    float* pin  = (l & 1) ? pf1 : pf0;
    float* pout = (l & 1) ? pf0 : pf1;

    agg_kernel<<<(N+3)/4, 256, 0, stream>>>(
        rowptr, perm, pin, Ab, Bb,
        ew1, (long)l*257*128 + 256*128,
        w2p + l*128, c2p + l, pparm + l*4,
        Hb, pout, N, flag);
    mm_hidden_kernel<<<MMGRID, 256, 65536, stream>>>(
        xb, Hb, NW1a, W12p, nb1, (long)l*128, degf, ebW + l*128, hb, flag);
    if (l < 3){
      mm_res_kernel<0><<<RGRID, 256, 32768, stream>>>(
          hb, NW2p, nb2, (long)l*128, xb, nullptr, nullptr, nullptr, flag);
      mm_ab_kernel<<<MMGRID, 256, 65536, stream>>>(
          xb, pk + ((l+1)*6+0)*16384, pk + ((l+1)*6+1)*16384,
          eb1, (long)(l+1)*128, Ab, Bb, flag);
    } else {
      mm_res_kernel<1><<<RGRID, 256, 32768, stream>>>(
          hb, NW2p, nb2, (long)l*128, xb, lng, lnb, d_out, flag);
    }
  }
}